// Round 10
// baseline (751.499 us; speedup 1.0000x reference)
//
#include <hip/hip_runtime.h>
#include <hip/hip_bf16.h>

#define CDIM 256
#define NH 8
#define HDIM 32

typedef short bf8 __attribute__((ext_vector_type(8)));
typedef float f32x4 __attribute__((ext_vector_type(4)));
typedef float f32x2 __attribute__((ext_vector_type(2)));

__device__ __forceinline__ float bf2f(ushort u) {
  union { unsigned int i; float f; } x; x.i = ((unsigned int)u) << 16; return x.f;
}
__device__ __forceinline__ ushort f2bf(float f) {
  union { float f; unsigned int i; } x; x.f = f;
  unsigned int lsb = (x.i >> 16) & 1u;
  unsigned int r = x.i + 0x7fffu + lsb;
  return (ushort)(r >> 16);
}

// ---------------- fp8 e4m3fn helpers (HW converts; guarded SW fallback) ----------------
__device__ __forceinline__ float dec_e4m3_sw(unsigned int b) {
  unsigned int s = b >> 7, e = (b >> 3) & 15, m = b & 7;
  float v = (e == 0) ? (float)m * 0.001953125f
                     : (float)(8 + m) * 0.125f * exp2f((float)((int)e - 7));
  return s ? -v : v;
}
__device__ __forceinline__ unsigned char enc_e4m3_sw(float f) {
  union { float f; unsigned int u; } x; x.f = f;
  unsigned int s = (x.u >> 31) << 7;
  float a = fabsf(f);
  if (!(a > 0.f)) return (unsigned char)s;
  if (a > 448.f) a = 448.f;
  int e = 0; float mant = frexpf(a, &e);
  int E = e + 6;
  unsigned int out;
  if (E <= 0) {
    int m = (int)rintf(a * 512.f);
    out = (m > 7) ? (s | (1u << 3)) : (s | (unsigned)m);
  } else {
    int m = (int)rintf(mant * 16.f);
    if (m == 16) { m = 8; E++; }
    if (E > 15 || (E == 15 && m - 8 > 6)) { E = 15; m = 14; }
    out = s | ((unsigned)E << 3) | (unsigned)(m - 8);
  }
  return (unsigned char)out;
}
template <bool HI>
__device__ __forceinline__ f32x2 fp8x2_f32(unsigned int w) {
#if __has_builtin(__builtin_amdgcn_cvt_pk_f32_fp8)
  return __builtin_amdgcn_cvt_pk_f32_fp8(w, HI);
#else
  unsigned int b0 = HI ? ((w >> 16) & 0xffu) : (w & 0xffu);
  unsigned int b1 = HI ? (w >> 24) : ((w >> 8) & 0xffu);
  f32x2 r; r[0] = dec_e4m3_sw(b0); r[1] = dec_e4m3_sw(b1); return r;
#endif
}
__device__ __forceinline__ unsigned char f32_fp8(float f) {
#if __has_builtin(__builtin_amdgcn_cvt_pk_fp8_f32)
  return (unsigned char)(__builtin_amdgcn_cvt_pk_fp8_f32(f, f, 0, false) & 0xff);
#else
  return enc_e4m3_sw(f);
#endif
}

// fast gelu (tanh form): max err ~2e-4 where pre-acts live (sigma~0.32).
__device__ __forceinline__ float fast_gelu(float t) {
  float u = 0.7978845608028654f * (t + 0.044715f * t * t * t);
  float ez = __expf(2.f * u);
  float th = 1.f - 2.f * __builtin_amdgcn_rcpf(ez + 1.f);
  return 0.5f * t * (1.f + th);
}

// async global->LDS, 16B per lane; LDS dest = wave-uniform base + lane*16.
__device__ __forceinline__ void gload_lds16(const ushort* g, ushort* l) {
  __builtin_amdgcn_global_load_lds((const __attribute__((address_space(1))) unsigned int*)g,
                                   (__attribute__((address_space(3))) unsigned int*)l,
                                   16, 0, 0);
}

// ---------------- casts fp32 -> bf16 (vectorized) ----------------
__global__ void k_cast4(const float4* __restrict__ s, ushort4* __restrict__ d, int n4) {
  int i = blockIdx.x * blockDim.x + threadIdx.x;
  if (i < n4) {
    float4 v = s[i];
    ushort4 o;
    o.x = f2bf(v.x); o.y = f2bf(v.y); o.z = f2bf(v.z); o.w = f2bf(v.w);
    d[i] = o;
  }
}

// ---------------- CSR build ----------------
__global__ void k_hist(const int* __restrict__ dst, int E, int* __restrict__ deg) {
  int i = blockIdx.x * blockDim.x + threadIdx.x;
  if (i < E) atomicAdd(&deg[dst[i]], 1);
}

__global__ __launch_bounds__(1024) void k_scan1(const int* __restrict__ deg, int N,
                                                int* __restrict__ rowptr, int* __restrict__ bsum) {
  __shared__ int s[1024];
  int t = threadIdx.x;
  int i = blockIdx.x * 1024 + t;
  int val = (i < N) ? deg[i] : 0;
  s[t] = val;
  __syncthreads();
  for (int off = 1; off < 1024; off <<= 1) {
    int add = (t >= off) ? s[t - off] : 0;
    __syncthreads();
    s[t] += add;
    __syncthreads();
  }
  if (i < N) rowptr[i + 1] = s[t];
  if (t == 1023) bsum[blockIdx.x] = s[t];
}

__global__ void k_scan2(int* __restrict__ bsum, int nb) {
  if (threadIdx.x == 0 && blockIdx.x == 0) {
    int run = 0;
    for (int j = 0; j < nb; ++j) { int t = bsum[j]; bsum[j] = run; run += t; }
  }
}

__global__ void k_scan3(int* __restrict__ rowptr, const int* __restrict__ bsum, int N) {
  int i = blockIdx.x * blockDim.x + threadIdx.x;
  if (i < N) rowptr[i + 1] += bsum[i >> 10];
  if (i == 0) rowptr[0] = 0;
}

__global__ void k_scatter(const int* __restrict__ src, const int* __restrict__ dst, int E,
                          const int* __restrict__ rowptr, int* __restrict__ cur,
                          int* __restrict__ csr_src) {
  int i = blockIdx.x * blockDim.x + threadIdx.x;
  if (i < E) {
    int d = dst[i];
    int pos = rowptr[d] + atomicAdd(&cur[d], 1);
    csr_src[pos] = src[i];
  }
}

// ---------------- staged 128x256 GEMM core (512 threads / 8 waves) ----------------
// Double-buffered LDS (T3/T4 minimum 2-phase): stage tile t+1 BEFORE computing
// tile t, single __syncthreads() per step. The vmcnt(0) drain at the barrier
// lands AFTER compute consumed its ds_reads, so staging latency hides under
// the MFMAs instead of being serialized (old: 2 barriers/step, zero overlap).
// Swizzle: LDS granule (row, slot) holds src granule (row, slot^(row&3)) —
// involution on SOURCE address here and on the READ below (G21).
__device__ __forceinline__ void stageA8(const ushort* __restrict__ S, int ld,
                                        int r0, int nr, int k0,
                                        ushort* lds, int wave, int lane) {
  int g = wave * 64 + lane;           // granule 0..511 (128 rows x 4 slots)
  int row = g >> 2, slot = g & 3;
  int rr = r0 + row; rr = (rr < nr) ? rr : (nr - 1);
  const ushort* src = S + (size_t)rr * ld + k0 + ((slot ^ (row & 3)) << 3);
  gload_lds16(src, &lds[(size_t)(wave * 64) * 8]);
}

__device__ __forceinline__ void stageB8(const ushort* __restrict__ S, int ld,
                                        int r0, int nr, int k0,
                                        ushort* lds, int wave, int lane) {
#pragma unroll
  for (int j = 0; j < 2; ++j) {
    int g = wave * 128 + j * 64 + lane;  // granule 0..1023 (256 rows x 4 slots)
    int row = g >> 2, slot = g & 3;
    int rr = r0 + row; rr = (rr < nr) ? rr : (nr - 1);
    const ushort* src = S + (size_t)rr * ld + k0 + ((slot ^ (row & 3)) << 3);
    gload_lds16(src, &lds[(size_t)(wave * 128 + j * 64) * 8]);
  }
}

// Wave w: rows (w&1)*64, cols (w>>1)*64 of the 128x256 block tile.
// lA: 2 x 128x32 buffers; lB: 2 x 256x32 buffers.
__device__ __forceinline__ void gemm256_core(const ushort* __restrict__ A, int lda, int rowt, int nA,
                                             const ushort* __restrict__ B, int ldb, int colt, int nB,
                                             int K, ushort* lA, ushort* lB, f32x4* acc) {
  int tid = threadIdx.x;
  int wave = tid >> 6, lane = tid & 63;
  int m = lane & 15, quad = lane >> 4;
  int r0w = (wave & 1) * 64, c0w = (wave >> 1) * 64;
  int sw = (quad ^ (m & 3)) << 3;  // swizzled 16B slot (in ushorts)

  int nt = K >> 5;
  // prologue: stage tile 0 into buffer 0
  stageA8(A, lda, rowt, nA, 0, lA, wave, lane);
  stageB8(B, ldb, colt, nB, 0, lB, wave, lane);
  __syncthreads();

  int cur = 0;
  for (int t = 0; t < nt; ++t) {
    // issue next tile's loads into the other buffer (latency hides under compute)
    if (t + 1 < nt) {
      stageA8(A, lda, rowt, nA, (t + 1) << 5, lA + (cur ^ 1) * (128 * 32), wave, lane);
      stageB8(B, ldb, colt, nB, (t + 1) << 5, lB + (cur ^ 1) * (256 * 32), wave, lane);
    }

    const ushort* cA = lA + cur * (128 * 32);
    const ushort* cB = lB + cur * (256 * 32);
    bf8 a[4], b[4];
#pragma unroll
    for (int ri = 0; ri < 4; ++ri)
      a[ri] = *(const bf8*)&cA[(r0w + ri * 16 + m) * 32 + sw];
#pragma unroll
    for (int cj = 0; cj < 4; ++cj)
      b[cj] = *(const bf8*)&cB[(c0w + cj * 16 + m) * 32 + sw];
#pragma unroll
    for (int ri = 0; ri < 4; ++ri)
#pragma unroll
      for (int cj = 0; cj < 4; ++cj)
        acc[ri * 4 + cj] = __builtin_amdgcn_mfma_f32_16x16x32_bf16(a[ri], b[cj], acc[ri * 4 + cj], 0, 0, 0);

    __syncthreads();  // drains vmcnt(0): next tile staged; this tile's reads done
    cur ^= 1;
  }
}

// fused QKV: q (bf16) | k,v (fp8). Grid (391, 3); blockIdx.y picks q/k/v.
__global__ __launch_bounds__(512) void k_qkvf(const ushort* __restrict__ featb,
                                              const ushort* __restrict__ Wqkv,
                                              const float* __restrict__ bq, const float* __restrict__ bk,
                                              const float* __restrict__ bv,
                                              ushort* __restrict__ q,
                                              unsigned char* __restrict__ k8,
                                              unsigned char* __restrict__ v8, int N) {
  __shared__ ushort lA[2 * 128 * 32];
  __shared__ ushort lB[2 * 256 * 32];
  int rowt = blockIdx.x * 128;
  int which = blockIdx.y;
  const float* bias = (which == 0) ? bq : (which == 1) ? bk : bv;
  int tid = threadIdx.x;
  int wave = tid >> 6, lane = tid & 63, m = lane & 15, quad = lane >> 4;
  int r0w = (wave & 1) * 64, c0w = (wave >> 1) * 64;

  f32x4 acc[16];
#pragma unroll
  for (int j = 0; j < 16; ++j) acc[j] = (f32x4){0.f, 0.f, 0.f, 0.f};

  gemm256_core(featb, CDIM, rowt, N, Wqkv + (size_t)which * 256 * CDIM, CDIM, 0, 256,
               CDIM, lA, lB, acc);

  unsigned char* o8 = (which == 1) ? k8 : v8;
#pragma unroll
  for (int cj = 0; cj < 4; ++cj) {
    int col = c0w + cj * 16 + m;
    float bs = bias[col];
#pragma unroll
    for (int ri = 0; ri < 4; ++ri)
#pragma unroll
      for (int i = 0; i < 4; ++i) {
        int r = rowt + r0w + ri * 16 + quad * 4 + i;
        if (r < N) {
          float vv = acc[ri * 4 + cj][i] + bs;
          if (which == 0) q[(size_t)r * CDIM + col] = f2bf(vv);
          else            o8[(size_t)r * CDIM + col] = f32_fp8(vv);
        }
      }
  }
}

// x = feat + wv @ Wp^T + bp  (fp32 out). Grid (391).
__global__ __launch_bounds__(512) void k_proj(const ushort* __restrict__ wv,
                                              const ushort* __restrict__ Wp,
                                              const float* __restrict__ bp,
                                              const float* __restrict__ feat,
                                              float* __restrict__ x, int N) {
  __shared__ ushort lA[2 * 128 * 32];
  __shared__ ushort lB[2 * 256 * 32];
  int rowt = blockIdx.x * 128;
  int tid = threadIdx.x;
  int wave = tid >> 6, lane = tid & 63, m = lane & 15, quad = lane >> 4;
  int r0w = (wave & 1) * 64, c0w = (wave >> 1) * 64;

  f32x4 acc[16];
#pragma unroll
  for (int j = 0; j < 16; ++j) acc[j] = (f32x4){0.f, 0.f, 0.f, 0.f};

  gemm256_core(wv, CDIM, rowt, N, Wp, CDIM, 0, 256, CDIM, lA, lB, acc);

#pragma unroll
  for (int cj = 0; cj < 4; ++cj) {
    int col = c0w + cj * 16 + m;
    float bs = bp[col];
#pragma unroll
    for (int ri = 0; ri < 4; ++ri)
#pragma unroll
      for (int i = 0; i < 4; ++i) {
        int r = rowt + r0w + ri * 16 + quad * 4 + i;
        if (r < N)
          x[(size_t)r * CDIM + col] = acc[ri * 4 + cj][i] + bs + feat[(size_t)r * CDIM + col];
      }
  }
}

// hidden-chunk GEMM: hid[., colt..colt+256) = gelu(h @ W1c^T + b1c). Grid (391, 2).
__global__ __launch_bounds__(512) void k_g1(const ushort* __restrict__ h,
                                            const ushort* __restrict__ W1c,
                                            const float* __restrict__ b1c,
                                            ushort* __restrict__ hid, int N) {
  __shared__ ushort lA[2 * 128 * 32];
  __shared__ ushort lB[2 * 256 * 32];
  int rowt = blockIdx.x * 128, colt = blockIdx.y * 256;
  int tid = threadIdx.x;
  int wave = tid >> 6, lane = tid & 63, m = lane & 15, quad = lane >> 4;
  int r0w = (wave & 1) * 64, c0w = (wave >> 1) * 64;

  f32x4 acc[16];
#pragma unroll
  for (int j = 0; j < 16; ++j) acc[j] = (f32x4){0.f, 0.f, 0.f, 0.f};

  gemm256_core(h, CDIM, rowt, N, W1c, CDIM, colt, 512, CDIM, lA, lB, acc);

#pragma unroll
  for (int cj = 0; cj < 4; ++cj) {
    int col = colt + c0w + cj * 16 + m;  // hidden-local col, < 512
    float bs = b1c[col];
#pragma unroll
    for (int ri = 0; ri < 4; ++ri)
#pragma unroll
      for (int i = 0; i < 4; ++i) {
        int r = rowt + r0w + ri * 16 + quad * 4 + i;
        if (r < N) hid[(size_t)r * 512 + col] = f2bf(fast_gelu(acc[ri * 4 + cj][i] + bs));
      }
  }
}

// out-chunk GEMM: out += hid @ W2c^T (+ b2 on first pass). Grid (391).
__global__ __launch_bounds__(512) void k_g2(const ushort* __restrict__ hid,
                                            const ushort* __restrict__ W2c,
                                            const float* __restrict__ b2,
                                            float* __restrict__ out, int N, int first) {
  __shared__ ushort lA[2 * 128 * 32];
  __shared__ ushort lB[2 * 256 * 32];
  int rowt = blockIdx.x * 128;
  int tid = threadIdx.x;
  int wave = tid >> 6, lane = tid & 63, m = lane & 15, quad = lane >> 4;
  int r0w = (wave & 1) * 64, c0w = (wave >> 1) * 64;

  f32x4 acc[16];
#pragma unroll
  for (int j = 0; j < 16; ++j) acc[j] = (f32x4){0.f, 0.f, 0.f, 0.f};

  gemm256_core(hid, 512, rowt, N, W2c, 1024, 0, 256, 512, lA, lB, acc);

#pragma unroll
  for (int cj = 0; cj < 4; ++cj) {
    int col = c0w + cj * 16 + m;
    float bs = first ? b2[col] : 0.f;
#pragma unroll
    for (int ri = 0; ri < 4; ++ri)
#pragma unroll
      for (int i = 0; i < 4; ++i) {
        int r = rowt + r0w + ri * 16 + quad * 4 + i;
        if (r < N) {
          size_t idx = (size_t)r * CDIM + col;
          out[idx] = out[idx] + acc[ri * 4 + cj][i] + bs;
        }
      }
  }
}

// fused segment softmax + aggregate, wave-per-dst, barrier-free, fp8 K/V,
// one-chunk software prefetch of csr_src + K rows + V rows (G7).
__global__ __launch_bounds__(256) void k_edge_agg(const ushort* __restrict__ q,
                                                  const unsigned char* __restrict__ kk8,
                                                  const unsigned char* __restrict__ vv8,
                                                  const int* __restrict__ rowptr,
                                                  const int* __restrict__ csr_src,
                                                  int N,
                                                  ushort* __restrict__ wv) {
  int wave = threadIdx.x >> 6, lane = threadIdx.x & 63;
  int n = blockIdx.x * 4 + wave;
  if (n >= N) return;  // wave-uniform; no barriers in this kernel

  int el = lane >> 3, h = lane & 7;
  int beg = rowptr[n], end = rowptr[n + 1];
  int deg = end - beg;

  // q slice for head h into registers (f32)
  float qf[32];
  {
    const ushort* qp = q + (size_t)n * CDIM + h * HDIM;
#pragma unroll
    for (int g = 0; g < 4; ++g) {
      bf8 qv = *(const bf8*)(qp + g * 8);
#pragma unroll
      for (int j = 0; j < 8; ++j) qf[g * 8 + j] = bf2f((ushort)qv[j]);
    }
  }

  float accv[4] = {0.f, 0.f, 0.f, 0.f};
  float den_part = 0.f;

  // prefetch chunk 0: src, K row (32B), V rows (this lane's dword of 8 edges)
  int src_n = (el < deg) ? csr_src[beg + el] : 0;
  const unsigned char* kp0 = kk8 + (size_t)src_n * CDIM + h * HDIM;
  uint4 w0_n = *(const uint4*)kp0;
  uint4 w1_n = *(const uint4*)(kp0 + 16);
  unsigned int vw_n[8];
#pragma unroll
  for (int j = 0; j < 8; ++j) {
    int sj = __shfl(src_n, j << 3);
    vw_n[j] = *(const unsigned int*)(vv8 + (size_t)sj * CDIM + lane * 4);
  }

  for (int c0 = 0; c0 < deg; c0 += 8) {
    uint4 w0 = w0_n, w1 = w1_n;
    unsigned int vw[8];
#pragma unroll
    for (int j = 0; j < 8; ++j) vw[j] = vw_n[j];
    bool vcur = (c0 + el < deg);

    // issue next chunk's loads before consuming this chunk (latency overlap)
    src_n = (c0 + 8 + el < deg) ? csr_src[beg + c0 + 8 + el] : 0;
    const unsigned char* kpn = kk8 + (size_t)src_n * CDIM + h * HDIM;
    w0_n = *(const uint4*)kpn;
    w1_n = *(const uint4*)(kpn + 16);
#pragma unroll
    for (int j = 0; j < 8; ++j) {
      int sj = __shfl(src_n, j << 3);
      vw_n[j] = *(const unsigned int*)(vv8 + (size_t)sj * CDIM + lane * 4);
    }

    float e = 0.f;
    if (vcur) {
      unsigned int ws[8] = {w0.x, w0.y, w0.z, w0.w, w1.x, w1.y, w1.z, w1.w};
      float dot = 0.f;
#pragma unroll
      for (int j = 0; j < 8; ++j) {
        f32x2 lo = fp8x2_f32<false>(ws[j]);
        f32x2 hi = fp8x2_f32<true>(ws[j]);
        dot = fmaf(qf[j * 4 + 0], lo[0], dot);
        dot = fmaf(qf[j * 4 + 1], lo[1], dot);
        dot = fmaf(qf[j * 4 + 2], hi[0], dot);
        dot = fmaf(qf[j * 4 + 3], hi[1], dot);
      }
      float s = dot * 0.17677669529663687f;  // 1/sqrt(32)
      s = fminf(10.f, fmaxf(-10.f, s));
      e = __expf(s - 10.f);  // fixed shift: scores clamped, softmax shift-invariant
    }
    den_part += e;

    // aggregate: lane's 4 channels of prefetched V[src_j], weight e_j[head]
#pragma unroll
    for (int j = 0; j < 8; ++j) {
      float ej = __shfl(e, (j << 3) | (lane >> 3));
      f32x2 lo = fp8x2_f32<false>(vw[j]);
      f32x2 hi = fp8x2_f32<true>(vw[j]);
      accv[0] = fmaf(ej, lo[0], accv[0]);
      accv[1] = fmaf(ej, lo[1], accv[1]);
      accv[2] = fmaf(ej, hi[0], accv[2]);
      accv[3] = fmaf(ej, hi[1], accv[3]);
    }
  }

  // den[h] = sum over el lanes (xor over bits 3..5), broadcast to channel lanes
  float den = den_part;
  den += __shfl_xor(den, 8);
  den += __shfl_xor(den, 16);
  den += __shfl_xor(den, 32);
  float denh = __shfl(den, lane >> 3);

  float inv = (deg > 0) ? (1.f / denh) : 0.f;
  ushort4 o;
  o.x = f2bf(accv[0] * inv);
  o.y = f2bf(accv[1] * inv);
  o.z = f2bf(accv[2] * inv);
  o.w = f2bf(accv[3] * inv);
  *(ushort4*)(wv + (size_t)n * CDIM + lane * 4) = o;
}

// h = layernorm(x)*g + b -> bf16 ; ALSO copies x into out (residual base),
// freeing the x region for the hidden-chunk buffer.
__global__ __launch_bounds__(256) void k_ln(const float* __restrict__ x,
                                            const float* __restrict__ g,
                                            const float* __restrict__ b,
                                            ushort* __restrict__ h,
                                            float* __restrict__ out) {
  int row = blockIdx.x * 4 + (threadIdx.x >> 6);
  int lane = threadIdx.x & 63;
  const float* xr = x + (size_t)row * CDIM;
  float4 xv = *(const float4*)(xr + lane * 4);
  *(float4*)(out + (size_t)row * CDIM + lane * 4) = xv;  // out = x
  float s = xv.x + xv.y + xv.z + xv.w;
  float ss = xv.x * xv.x + xv.y * xv.y + xv.z * xv.z + xv.w * xv.w;
#pragma unroll
  for (int msk = 1; msk <= 32; msk <<= 1) {
    s += __shfl_xor(s, msk);
    ss += __shfl_xor(ss, msk);
  }
  float mu = s * (1.f / CDIM);
  float var = ss * (1.f / CDIM) - mu * mu;
  float rs = rsqrtf(var + 1e-5f);
  float xe[4] = {xv.x, xv.y, xv.z, xv.w};
#pragma unroll
  for (int t = 0; t < 4; ++t) {
    int cc = lane * 4 + t;
    h[(size_t)row * CDIM + cc] = f2bf((xe[t] - mu) * rs * g[cc] + b[cc]);
  }
}

extern "C" void kernel_launch(void* const* d_in, const int* in_sizes, int n_in,
                              void* d_out, int out_size, void* d_ws, size_t ws_size,
                              hipStream_t stream) {
  const float* feat = (const float*)d_in[0];
  const int* esrc = (const int*)d_in[1];
  const int* edst = (const int*)d_in[2];
  const float* Wq = (const float*)d_in[3];
  const float* bq = (const float*)d_in[4];
  const float* Wk = (const float*)d_in[5];
  const float* bk = (const float*)d_in[6];
  const float* Wv = (const float*)d_in[7];
  const float* bv = (const float*)d_in[8];
  const float* Wp = (const float*)d_in[9];
  const float* bp = (const float*)d_in[10];
  const float* lng = (const float*)d_in[11];
  const float* lnb = (const float*)d_in[12];
  const float* W1 = (const float*)d_in[13];
  const float* b1 = (const float*)d_in[14];
  const float* W2 = (const float*)d_in[15];
  const float* b2 = (const float*)d_in[16];

  const int N = in_sizes[0] / CDIM;  // 50000
  const int E = in_sizes[1];         // 1600000
  const size_t NC2 = (size_t)N * CDIM * 2;  // bf16 plane: 25.6 MB
  const size_t NC1 = (size_t)N * CDIM;      // fp8 plane: 12.8 MB

  // Workspace layout (lifetime overlays):
  //   [0,NC2) q | x(f32, 2*NC2) overlays q+k8/v8 from proj on | hid overlays x after ln
  //   [NC2,2NC2) k8 (fp8) + v8 (fp8), each NC1 — dead before x is written
  //   [2NC2,3NC2) (free) | h(bf16) from ln on
  //   [3NC2,4NC2) wv | featb(bf16) overlays (disjoint lifetime)
  //   [4NC2,..) CSR, then bf16 weights (Wq,Wk,Wv contiguous = fused Wqkv)
  char* w = (char*)d_ws;
  ushort* q   = (ushort*)(w);
  unsigned char* k8 = (unsigned char*)(w + NC2);
  unsigned char* v8 = (unsigned char*)(w + NC2 + NC1);
  ushort* wvb = (ushort*)(w + 3 * NC2);
  ushort* featb = (ushort*)(w + 3 * NC2);
  float*  x   = (float*)(w);               // overlays q+k8+v8
  ushort* h   = (ushort*)(w + 2 * NC2);
  ushort* hid = (ushort*)(w);              // overlays x (dead after k_ln)

  char* csr = w + 4 * NC2;
  int* rowptr  = (int*)(csr);
  int* deg     = (int*)(csr + 200064);
  int* csr_src = (int*)(csr + 400128);
  int* bsum    = (int*)(csr + 400128 + (size_t)E * 4);

  char* wb = csr + 400128 + (size_t)E * 4 + 256;
  ushort* Wqb = (ushort*)(wb);
  ushort* Wkb = (ushort*)(wb + 131072);
  ushort* Wvb = (ushort*)(wb + 262144);
  ushort* Wpb = (ushort*)(wb + 393216);
  ushort* W1b = (ushort*)(wb + 524288);
  ushort* W2b = (ushort*)(wb + 1048576);

  const int nb = (N + 1023) / 1024;
  const int RT128 = (N + 127) / 128; // 391

  // weight + feat casts (Wq/Wk/Wv land contiguously -> fused Wqkv matrix)
  k_cast4<<<(16384 + 255) / 256, 256, 0, stream>>>((const float4*)Wq, (ushort4*)Wqb, 16384);
  k_cast4<<<(16384 + 255) / 256, 256, 0, stream>>>((const float4*)Wk, (ushort4*)Wkb, 16384);
  k_cast4<<<(16384 + 255) / 256, 256, 0, stream>>>((const float4*)Wv, (ushort4*)Wvb, 16384);
  k_cast4<<<(16384 + 255) / 256, 256, 0, stream>>>((const float4*)Wp, (ushort4*)Wpb, 16384);
  k_cast4<<<(65536 + 255) / 256, 256, 0, stream>>>((const float4*)W1, (ushort4*)W1b, 65536);
  k_cast4<<<(65536 + 255) / 256, 256, 0, stream>>>((const float4*)W2, (ushort4*)W2b, 65536);
  {
    int n4 = N * CDIM / 4;
    k_cast4<<<(n4 + 255) / 256, 256, 0, stream>>>((const float4*)feat, (ushort4*)featb, n4);
  }

  // CSR build (group edges by dst)
  hipMemsetAsync(deg, 0, (size_t)N * 4, stream);
  k_hist<<<(E + 255) / 256, 256, 0, stream>>>(edst, E, deg);
  k_scan1<<<nb, 1024, 0, stream>>>(deg, N, rowptr, bsum);
  k_scan2<<<1, 64, 0, stream>>>(bsum, nb);
  k_scan3<<<(N + 255) / 256, 256, 0, stream>>>(rowptr, bsum, N);
  hipMemsetAsync(deg, 0, (size_t)N * 4, stream);
  k_scatter<<<(E + 255) / 256, 256, 0, stream>>>(esrc, edst, E, rowptr, deg, csr_src);

  // fused QKV projection (q bf16; k/v fp8 planes), 128x256 dbuf blocks
  k_qkvf<<<dim3(RT128, 3), 512, 0, stream>>>(featb, Wqb, bq, bk, bv, q, k8, v8, N);
  // fused segment-softmax + aggregate (wave-per-dst, prefetched fp8 gathers)
  k_edge_agg<<<(N + 3) / 4, 256, 0, stream>>>(q, k8, v8, rowptr, csr_src, N, wvb);
  // x = feat + wv@Wp^T + bp
  k_proj<<<RT128, 512, 0, stream>>>(wvb, Wpb, bp, feat, x, N);
  // h = LN(x); out = x (residual base; x region then free for hid)
  k_ln<<<N / 4, 256, 0, stream>>>(x, lng, lnb, h, (float*)d_out);

  // MLP: hidden in 2 passes of 512 cols; 128x256 dbuf staged GEMMs.
  for (int c = 0; c < 2; ++c) {
    k_g1<<<dim3(RT128, 2), 512, 0, stream>>>(h, W1b + (size_t)c * 512 * CDIM,
                                             b1 + c * 512, hid, N);
    k_g2<<<RT128, 512, 0, stream>>>(hid, W2b + (size_t)c * 512,
                                    b2, (float*)d_out, N, c == 0 ? 1 : 0);
  }
}

// Round 11
// 687.257 us; speedup vs baseline: 1.0935x; 1.0935x over previous
//
#include <hip/hip_runtime.h>
#include <hip/hip_bf16.h>

#define CDIM 256
#define NH 8
#define HDIM 32

typedef short bf8 __attribute__((ext_vector_type(8)));
typedef float f32x4 __attribute__((ext_vector_type(4)));
typedef float f32x2 __attribute__((ext_vector_type(2)));

__device__ __forceinline__ float bf2f(ushort u) {
  union { unsigned int i; float f; } x; x.i = ((unsigned int)u) << 16; return x.f;
}
__device__ __forceinline__ ushort f2bf(float f) {
  union { float f; unsigned int i; } x; x.f = f;
  unsigned int lsb = (x.i >> 16) & 1u;
  unsigned int r = x.i + 0x7fffu + lsb;
  return (ushort)(r >> 16);
}

// ---------------- fp8 e4m3fn helpers (HW converts; guarded SW fallback) ----------------
__device__ __forceinline__ float dec_e4m3_sw(unsigned int b) {
  unsigned int s = b >> 7, e = (b >> 3) & 15, m = b & 7;
  float v = (e == 0) ? (float)m * 0.001953125f
                     : (float)(8 + m) * 0.125f * exp2f((float)((int)e - 7));
  return s ? -v : v;
}
__device__ __forceinline__ unsigned char enc_e4m3_sw(float f) {
  union { float f; unsigned int u; } x; x.f = f;
  unsigned int s = (x.u >> 31) << 7;
  float a = fabsf(f);
  if (!(a > 0.f)) return (unsigned char)s;
  if (a > 448.f) a = 448.f;
  int e = 0; float mant = frexpf(a, &e);
  int E = e + 6;
  unsigned int out;
  if (E <= 0) {
    int m = (int)rintf(a * 512.f);
    out = (m > 7) ? (s | (1u << 3)) : (s | (unsigned)m);
  } else {
    int m = (int)rintf(mant * 16.f);
    if (m == 16) { m = 8; E++; }
    if (E > 15 || (E == 15 && m - 8 > 6)) { E = 15; m = 14; }
    out = s | ((unsigned)E << 3) | (unsigned)(m - 8);
  }
  return (unsigned char)out;
}
template <bool HI>
__device__ __forceinline__ f32x2 fp8x2_f32(unsigned int w) {
#if __has_builtin(__builtin_amdgcn_cvt_pk_f32_fp8)
  return __builtin_amdgcn_cvt_pk_f32_fp8(w, HI);
#else
  unsigned int b0 = HI ? ((w >> 16) & 0xffu) : (w & 0xffu);
  unsigned int b1 = HI ? (w >> 24) : ((w >> 8) & 0xffu);
  f32x2 r; r[0] = dec_e4m3_sw(b0); r[1] = dec_e4m3_sw(b1); return r;
#endif
}
__device__ __forceinline__ unsigned char f32_fp8(float f) {
#if __has_builtin(__builtin_amdgcn_cvt_pk_fp8_f32)
  return (unsigned char)(__builtin_amdgcn_cvt_pk_fp8_f32(f, f, 0, false) & 0xff);
#else
  return enc_e4m3_sw(f);
#endif
}

// fast gelu (tanh form): max err ~2e-4 where pre-acts live (sigma~0.32).
__device__ __forceinline__ float fast_gelu(float t) {
  float u = 0.7978845608028654f * (t + 0.044715f * t * t * t);
  float ez = __expf(2.f * u);
  float th = 1.f - 2.f * __builtin_amdgcn_rcpf(ez + 1.f);
  return 0.5f * t * (1.f + th);
}

// async global->LDS, 16B per lane; LDS dest = wave-uniform base + lane*16.
__device__ __forceinline__ void gload_lds16(const ushort* g, ushort* l) {
  __builtin_amdgcn_global_load_lds((const __attribute__((address_space(1))) unsigned int*)g,
                                   (__attribute__((address_space(3))) unsigned int*)l,
                                   16, 0, 0);
}

// ---------------- casts fp32 -> bf16 (vectorized) ----------------
__global__ void k_cast4(const float4* __restrict__ s, ushort4* __restrict__ d, int n4) {
  int i = blockIdx.x * blockDim.x + threadIdx.x;
  if (i < n4) {
    float4 v = s[i];
    ushort4 o;
    o.x = f2bf(v.x); o.y = f2bf(v.y); o.z = f2bf(v.z); o.w = f2bf(v.w);
    d[i] = o;
  }
}

// merged weight casts: blockIdx.y selects region (saves 5 launches).
__global__ void k_castw(const float4* __restrict__ s0, ushort4* __restrict__ d0,
                        const float4* __restrict__ s1, ushort4* __restrict__ d1,
                        const float4* __restrict__ s2, ushort4* __restrict__ d2,
                        const float4* __restrict__ s3, ushort4* __restrict__ d3,
                        const float4* __restrict__ s4, ushort4* __restrict__ d4,
                        const float4* __restrict__ s5, ushort4* __restrict__ d5) {
  int y = blockIdx.y;
  const float4* s; ushort4* d; int n4;
  switch (y) {
    case 0: s = s0; d = d0; n4 = 16384; break;
    case 1: s = s1; d = d1; n4 = 16384; break;
    case 2: s = s2; d = d2; n4 = 16384; break;
    case 3: s = s3; d = d3; n4 = 16384; break;
    case 4: s = s4; d = d4; n4 = 65536; break;
    default: s = s5; d = d5; n4 = 65536; break;
  }
  int i = blockIdx.x * blockDim.x + threadIdx.x;
  if (i < n4) {
    float4 v = s[i];
    ushort4 o;
    o.x = f2bf(v.x); o.y = f2bf(v.y); o.z = f2bf(v.z); o.w = f2bf(v.w);
    d[i] = o;
  }
}

// ---------------- CSR build ----------------
__global__ void k_hist(const int* __restrict__ dst, int E, int* __restrict__ deg) {
  int i = blockIdx.x * blockDim.x + threadIdx.x;
  if (i < E) atomicAdd(&deg[dst[i]], 1);
}

__global__ __launch_bounds__(1024) void k_scan1(const int* __restrict__ deg, int N,
                                                int* __restrict__ rowptr, int* __restrict__ bsum) {
  __shared__ int s[1024];
  int t = threadIdx.x;
  int i = blockIdx.x * 1024 + t;
  int val = (i < N) ? deg[i] : 0;
  s[t] = val;
  __syncthreads();
  for (int off = 1; off < 1024; off <<= 1) {
    int add = (t >= off) ? s[t - off] : 0;
    __syncthreads();
    s[t] += add;
    __syncthreads();
  }
  if (i < N) rowptr[i + 1] = s[t];
  if (t == 1023) bsum[blockIdx.x] = s[t];
}

__global__ void k_scan2(int* __restrict__ bsum, int nb) {
  if (threadIdx.x == 0 && blockIdx.x == 0) {
    int run = 0;
    for (int j = 0; j < nb; ++j) { int t = bsum[j]; bsum[j] = run; run += t; }
  }
}

__global__ void k_scan3(int* __restrict__ rowptr, const int* __restrict__ bsum, int N) {
  int i = blockIdx.x * blockDim.x + threadIdx.x;
  if (i < N) rowptr[i + 1] += bsum[i >> 10];
  if (i == 0) rowptr[0] = 0;
}

__global__ void k_scatter(const int* __restrict__ src, const int* __restrict__ dst, int E,
                          const int* __restrict__ rowptr, int* __restrict__ cur,
                          int* __restrict__ csr_src) {
  int i = blockIdx.x * blockDim.x + threadIdx.x;
  if (i < E) {
    int d = dst[i];
    int pos = rowptr[d] + atomicAdd(&cur[d], 1);
    csr_src[pos] = src[i];
  }
}

// ---------------- staged 128x256 GEMM core (512 threads / 8 waves) ----------------
// Round-9 proven version: single buffer, 2 barriers per BK=32 step. At 24 KB
// LDS this runs 4 blocks/CU; inter-block TLP hides staging latency (m114) —
// the r10 double-buffer cut residency to 3 and regressed.
// Swizzle: LDS granule (row, slot) holds src granule (row, slot^(row&3)) —
// involution on SOURCE address here and on the READ below (G21).
__device__ __forceinline__ void stageA8(const ushort* __restrict__ S, int ld,
                                        int r0, int nr, int k0,
                                        ushort* lds, int wave, int lane) {
  int g = wave * 64 + lane;           // granule 0..511 (128 rows x 4 slots)
  int row = g >> 2, slot = g & 3;
  int rr = r0 + row; rr = (rr < nr) ? rr : (nr - 1);
  const ushort* src = S + (size_t)rr * ld + k0 + ((slot ^ (row & 3)) << 3);
  gload_lds16(src, &lds[(size_t)(wave * 64) * 8]);
}

__device__ __forceinline__ void stageB8(const ushort* __restrict__ S, int ld,
                                        int r0, int nr, int k0,
                                        ushort* lds, int wave, int lane) {
#pragma unroll
  for (int j = 0; j < 2; ++j) {
    int g = wave * 128 + j * 64 + lane;  // granule 0..1023 (256 rows x 4 slots)
    int row = g >> 2, slot = g & 3;
    int rr = r0 + row; rr = (rr < nr) ? rr : (nr - 1);
    const ushort* src = S + (size_t)rr * ld + k0 + ((slot ^ (row & 3)) << 3);
    gload_lds16(src, &lds[(size_t)(wave * 128 + j * 64) * 8]);
  }
}

// Wave w: rows (w&1)*64, cols (w>>1)*64 of the 128x256 block tile.
__device__ __forceinline__ void gemm256_core(const ushort* __restrict__ A, int lda, int rowt, int nA,
                                             const ushort* __restrict__ B, int ldb, int colt, int nB,
                                             int K, ushort* lA, ushort* lB, f32x4* acc) {
  int tid = threadIdx.x;
  int wave = tid >> 6, lane = tid & 63;
  int m = lane & 15, quad = lane >> 4;
  int r0w = (wave & 1) * 64, c0w = (wave >> 1) * 64;
  int sw = (quad ^ (m & 3)) << 3;  // swizzled 16B slot (in ushorts)

  for (int k0 = 0; k0 < K; k0 += 32) {
    __syncthreads();  // prior step's LDS reads complete before overwrite
    stageA8(A, lda, rowt, nA, k0, lA, wave, lane);
    stageB8(B, ldb, colt, nB, k0, lB, wave, lane);
    __syncthreads();  // vmcnt(0) drained before barrier -> tiles ready

    bf8 a[4], b[4];
#pragma unroll
    for (int ri = 0; ri < 4; ++ri)
      a[ri] = *(const bf8*)&lA[(r0w + ri * 16 + m) * 32 + sw];
#pragma unroll
    for (int cj = 0; cj < 4; ++cj)
      b[cj] = *(const bf8*)&lB[(c0w + cj * 16 + m) * 32 + sw];
#pragma unroll
    for (int ri = 0; ri < 4; ++ri)
#pragma unroll
      for (int cj = 0; cj < 4; ++cj)
        acc[ri * 4 + cj] = __builtin_amdgcn_mfma_f32_16x16x32_bf16(a[ri], b[cj], acc[ri * 4 + cj], 0, 0, 0);
  }
}

// fused QKV: q (bf16) | k,v (fp8). Grid (391, 3); blockIdx.y picks q/k/v.
__global__ __launch_bounds__(512) void k_qkvf(const ushort* __restrict__ featb,
                                              const ushort* __restrict__ Wqkv,
                                              const float* __restrict__ bq, const float* __restrict__ bk,
                                              const float* __restrict__ bv,
                                              ushort* __restrict__ q,
                                              unsigned char* __restrict__ k8,
                                              unsigned char* __restrict__ v8, int N) {
  __shared__ ushort lA[128 * 32];
  __shared__ ushort lB[256 * 32];
  int rowt = blockIdx.x * 128;
  int which = blockIdx.y;
  const float* bias = (which == 0) ? bq : (which == 1) ? bk : bv;
  int tid = threadIdx.x;
  int wave = tid >> 6, lane = tid & 63, m = lane & 15, quad = lane >> 4;
  int r0w = (wave & 1) * 64, c0w = (wave >> 1) * 64;

  f32x4 acc[16];
#pragma unroll
  for (int j = 0; j < 16; ++j) acc[j] = (f32x4){0.f, 0.f, 0.f, 0.f};

  gemm256_core(featb, CDIM, rowt, N, Wqkv + (size_t)which * 256 * CDIM, CDIM, 0, 256,
               CDIM, lA, lB, acc);

  unsigned char* o8 = (which == 1) ? k8 : v8;
#pragma unroll
  for (int cj = 0; cj < 4; ++cj) {
    int col = c0w + cj * 16 + m;
    float bs = bias[col];
#pragma unroll
    for (int ri = 0; ri < 4; ++ri)
#pragma unroll
      for (int i = 0; i < 4; ++i) {
        int r = rowt + r0w + ri * 16 + quad * 4 + i;
        if (r < N) {
          float vv = acc[ri * 4 + cj][i] + bs;
          if (which == 0) q[(size_t)r * CDIM + col] = f2bf(vv);
          else            o8[(size_t)r * CDIM + col] = f32_fp8(vv);
        }
      }
  }
}

// x = feat + wv@Wp^T + bp, FUSED with LayerNorm: out = x; h = LN(x)*g + b.
// Each 128-row block holds complete rows (256 cols across 4 col-quadrant
// waves) -> row mean/var = in-register cj-sum + 16-lane shfl reduce +
// 4-quadrant LDS combine. Eliminates the x fp32 round-trip (102 MB).
__global__ __launch_bounds__(512) void k_projln(const ushort* __restrict__ wv,
                                                const ushort* __restrict__ Wp,
                                                const float* __restrict__ bp,
                                                const float* __restrict__ feat,
                                                const float* __restrict__ lng,
                                                const float* __restrict__ lnb,
                                                float* __restrict__ out,
                                                ushort* __restrict__ h, int N) {
  __shared__ ushort lA[128 * 32];
  __shared__ ushort lB[256 * 32];
  __shared__ float sred[2][128][4];  // [s|ss][block-row][col-quadrant]
  int rowt = blockIdx.x * 128;
  int tid = threadIdx.x;
  int wave = tid >> 6, lane = tid & 63, m = lane & 15, quad = lane >> 4;
  int r0w = (wave & 1) * 64, c0w = (wave >> 1) * 64;

  f32x4 acc[16];
#pragma unroll
  for (int j = 0; j < 16; ++j) acc[j] = (f32x4){0.f, 0.f, 0.f, 0.f};

  gemm256_core(wv, CDIM, rowt, N, Wp, CDIM, 0, 256, CDIM, lA, lB, acc);

  // acc <- x = acc + bp + feat (row-clamped feat read for tail rows)
#pragma unroll
  for (int cj = 0; cj < 4; ++cj) {
    int col = c0w + cj * 16 + m;
    float bs = bp[col];
#pragma unroll
    for (int ri = 0; ri < 4; ++ri)
#pragma unroll
      for (int i = 0; i < 4; ++i) {
        int r = rowt + r0w + ri * 16 + quad * 4 + i;
        int rr = (r < N) ? r : (N - 1);
        acc[ri * 4 + cj][i] += bs + feat[(size_t)rr * CDIM + col];
      }
  }

  // per-row partial sums over this wave's 64-col quadrant
#pragma unroll
  for (int ri = 0; ri < 4; ++ri)
#pragma unroll
    for (int i = 0; i < 4; ++i) {
      float s = acc[ri * 4 + 0][i] + acc[ri * 4 + 1][i] + acc[ri * 4 + 2][i] + acc[ri * 4 + 3][i];
      float ss = acc[ri * 4 + 0][i] * acc[ri * 4 + 0][i] + acc[ri * 4 + 1][i] * acc[ri * 4 + 1][i]
               + acc[ri * 4 + 2][i] * acc[ri * 4 + 2][i] + acc[ri * 4 + 3][i] * acc[ri * 4 + 3][i];
#pragma unroll
      for (int msk = 1; msk <= 8; msk <<= 1) {
        s += __shfl_xor(s, msk);
        ss += __shfl_xor(ss, msk);
      }
      if (m == 0) {
        int blrow = (wave & 1) * 64 + ri * 16 + quad * 4 + i;
        sred[0][blrow][wave >> 1] = s;
        sred[1][blrow][wave >> 1] = ss;
      }
    }
  __syncthreads();

  float mu_[16], rs_[16];
#pragma unroll
  for (int ri = 0; ri < 4; ++ri)
#pragma unroll
    for (int i = 0; i < 4; ++i) {
      int blrow = (wave & 1) * 64 + ri * 16 + quad * 4 + i;
      float S = sred[0][blrow][0] + sred[0][blrow][1] + sred[0][blrow][2] + sred[0][blrow][3];
      float SS = sred[1][blrow][0] + sred[1][blrow][1] + sred[1][blrow][2] + sred[1][blrow][3];
      float mu = S * (1.f / CDIM);
      float var = SS * (1.f / CDIM) - mu * mu;
      mu_[ri * 4 + i] = mu;
      rs_[ri * 4 + i] = rsqrtf(var + 1e-5f);
    }

#pragma unroll
  for (int cj = 0; cj < 4; ++cj) {
    int col = c0w + cj * 16 + m;
    float gc = lng[col], bc = lnb[col];
#pragma unroll
    for (int ri = 0; ri < 4; ++ri)
#pragma unroll
      for (int i = 0; i < 4; ++i) {
        int r = rowt + r0w + ri * 16 + quad * 4 + i;
        if (r < N) {
          float v = acc[ri * 4 + cj][i];
          out[(size_t)r * CDIM + col] = v;
          h[(size_t)r * CDIM + col] = f2bf((v - mu_[ri * 4 + i]) * rs_[ri * 4 + i] * gc + bc);
        }
      }
  }
}

// hidden-chunk GEMM: hid[., colt..colt+256) = gelu(h @ W1c^T + b1c). Grid (391, 2).
__global__ __launch_bounds__(512) void k_g1(const ushort* __restrict__ h,
                                            const ushort* __restrict__ W1c,
                                            const float* __restrict__ b1c,
                                            ushort* __restrict__ hid, int N) {
  __shared__ ushort lA[128 * 32];
  __shared__ ushort lB[256 * 32];
  int rowt = blockIdx.x * 128, colt = blockIdx.y * 256;
  int tid = threadIdx.x;
  int wave = tid >> 6, lane = tid & 63, m = lane & 15, quad = lane >> 4;
  int r0w = (wave & 1) * 64, c0w = (wave >> 1) * 64;

  f32x4 acc[16];
#pragma unroll
  for (int j = 0; j < 16; ++j) acc[j] = (f32x4){0.f, 0.f, 0.f, 0.f};

  gemm256_core(h, CDIM, rowt, N, W1c, CDIM, colt, 512, CDIM, lA, lB, acc);

#pragma unroll
  for (int cj = 0; cj < 4; ++cj) {
    int col = colt + c0w + cj * 16 + m;  // hidden-local col, < 512
    float bs = b1c[col];
#pragma unroll
    for (int ri = 0; ri < 4; ++ri)
#pragma unroll
      for (int i = 0; i < 4; ++i) {
        int r = rowt + r0w + ri * 16 + quad * 4 + i;
        if (r < N) hid[(size_t)r * 512 + col] = f2bf(fast_gelu(acc[ri * 4 + cj][i] + bs));
      }
  }
}

// out-chunk GEMM: out += hid @ W2c^T (+ b2 on first pass). Grid (391).
__global__ __launch_bounds__(512) void k_g2(const ushort* __restrict__ hid,
                                            const ushort* __restrict__ W2c,
                                            const float* __restrict__ b2,
                                            float* __restrict__ out, int N, int first) {
  __shared__ ushort lA[128 * 32];
  __shared__ ushort lB[256 * 32];
  int rowt = blockIdx.x * 128;
  int tid = threadIdx.x;
  int wave = tid >> 6, lane = tid & 63, m = lane & 15, quad = lane >> 4;
  int r0w = (wave & 1) * 64, c0w = (wave >> 1) * 64;

  f32x4 acc[16];
#pragma unroll
  for (int j = 0; j < 16; ++j) acc[j] = (f32x4){0.f, 0.f, 0.f, 0.f};

  gemm256_core(hid, 512, rowt, N, W2c, 1024, 0, 256, 512, lA, lB, acc);

#pragma unroll
  for (int cj = 0; cj < 4; ++cj) {
    int col = c0w + cj * 16 + m;
    float bs = first ? b2[col] : 0.f;
#pragma unroll
    for (int ri = 0; ri < 4; ++ri)
#pragma unroll
      for (int i = 0; i < 4; ++i) {
        int r = rowt + r0w + ri * 16 + quad * 4 + i;
        if (r < N) {
          size_t idx = (size_t)r * CDIM + col;
          out[idx] = out[idx] + acc[ri * 4 + cj][i] + bs;
        }
      }
  }
}

// fused segment softmax + aggregate, wave-per-dst, barrier-free, fp8 K/V,
// one-chunk software prefetch of csr_src + K rows (round-9 proven version).
__global__ __launch_bounds__(256) void k_edge_agg(const ushort* __restrict__ q,
                                                  const unsigned char* __restrict__ kk8,
                                                  const unsigned char* __restrict__ vv8,
                                                  const int* __restrict__ rowptr,
                                                  const int* __restrict__ csr_src,
                                                  int N,
                                                  ushort* __restrict__ wv) {
  int wave = threadIdx.x >> 6, lane = threadIdx.x & 63;
  int n = blockIdx.x * 4 + wave;
  if (n >= N) return;  // wave-uniform; no barriers in this kernel

  int el = lane >> 3, h = lane & 7;
  int beg = rowptr[n], end = rowptr[n + 1];
  int deg = end - beg;

  // q slice for head h into registers (f32)
  float qf[32];
  {
    const ushort* qp = q + (size_t)n * CDIM + h * HDIM;
#pragma unroll
    for (int g = 0; g < 4; ++g) {
      bf8 qv = *(const bf8*)(qp + g * 8);
#pragma unroll
      for (int j = 0; j < 8; ++j) qf[g * 8 + j] = bf2f((ushort)qv[j]);
    }
  }

  float accv[4] = {0.f, 0.f, 0.f, 0.f};
  float den_part = 0.f;

  // prefetch chunk 0 (invalid lanes read row 0 — harmless, e forced to 0)
  int src_n = (el < deg) ? csr_src[beg + el] : 0;
  const unsigned char* kp0 = kk8 + (size_t)src_n * CDIM + h * HDIM;
  uint4 w0_n = *(const uint4*)kp0;
  uint4 w1_n = *(const uint4*)(kp0 + 16);

  for (int c0 = 0; c0 < deg; c0 += 8) {
    int src = src_n;
    uint4 w0 = w0_n, w1 = w1_n;
    bool vcur = (c0 + el < deg);

    // issue next chunk's loads before consuming this chunk (latency overlap)
    src_n = (c0 + 8 + el < deg) ? csr_src[beg + c0 + 8 + el] : 0;
    const unsigned char* kpn = kk8 + (size_t)src_n * CDIM + h * HDIM;
    w0_n = *(const uint4*)kpn;
    w1_n = *(const uint4*)(kpn + 16);

    float e = 0.f;
    if (vcur) {
      unsigned int ws[8] = {w0.x, w0.y, w0.z, w0.w, w1.x, w1.y, w1.z, w1.w};
      float dot = 0.f;
#pragma unroll
      for (int j = 0; j < 8; ++j) {
        f32x2 lo = fp8x2_f32<false>(ws[j]);
        f32x2 hi = fp8x2_f32<true>(ws[j]);
        dot = fmaf(qf[j * 4 + 0], lo[0], dot);
        dot = fmaf(qf[j * 4 + 1], lo[1], dot);
        dot = fmaf(qf[j * 4 + 2], hi[0], dot);
        dot = fmaf(qf[j * 4 + 3], hi[1], dot);
      }
      float s = dot * 0.17677669529663687f;  // 1/sqrt(32)
      s = fminf(10.f, fmaxf(-10.f, s));
      e = __expf(s - 10.f);  // fixed shift: scores clamped, softmax shift-invariant
    }
    den_part += e;

    // aggregate these 8 edges: lane reads its 4 channels of V[src_j], weight e_j[head]
#pragma unroll
    for (int j = 0; j < 8; ++j) {
      int sj = __shfl(src, j << 3);
      float ej = __shfl(e, (j << 3) | (lane >> 3));
      unsigned int vw = *(const unsigned int*)(vv8 + (size_t)sj * CDIM + lane * 4);
      f32x2 lo = fp8x2_f32<false>(vw);
      f32x2 hi = fp8x2_f32<true>(vw);
      accv[0] = fmaf(ej, lo[0], accv[0]);
      accv[1] = fmaf(ej, lo[1], accv[1]);
      accv[2] = fmaf(ej, hi[0], accv[2]);
      accv[3] = fmaf(ej, hi[1], accv[3]);
    }
  }

  // den[h] = sum over el lanes (xor over bits 3..5), broadcast to channel lanes
  float den = den_part;
  den += __shfl_xor(den, 8);
  den += __shfl_xor(den, 16);
  den += __shfl_xor(den, 32);
  float denh = __shfl(den, lane >> 3);

  float inv = (deg > 0) ? (1.f / denh) : 0.f;
  ushort4 o;
  o.x = f2bf(accv[0] * inv);
  o.y = f2bf(accv[1] * inv);
  o.z = f2bf(accv[2] * inv);
  o.w = f2bf(accv[3] * inv);
  *(ushort4*)(wv + (size_t)n * CDIM + lane * 4) = o;
}

extern "C" void kernel_launch(void* const* d_in, const int* in_sizes, int n_in,
                              void* d_out, int out_size, void* d_ws, size_t ws_size,
                              hipStream_t stream) {
  const float* feat = (const float*)d_in[0];
  const int* esrc = (const int*)d_in[1];
  const int* edst = (const int*)d_in[2];
  const float* Wq = (const float*)d_in[3];
  const float* bq = (const float*)d_in[4];
  const float* Wk = (const float*)d_in[5];
  const float* bk = (const float*)d_in[6];
  const float* Wv = (const float*)d_in[7];
  const float* bv = (const float*)d_in[8];
  const float* Wp = (const float*)d_in[9];
  const float* bp = (const float*)d_in[10];
  const float* lng = (const float*)d_in[11];
  const float* lnb = (const float*)d_in[12];
  const float* W1 = (const float*)d_in[13];
  const float* b1 = (const float*)d_in[14];
  const float* W2 = (const float*)d_in[15];
  const float* b2 = (const float*)d_in[16];

  const int N = in_sizes[0] / CDIM;  // 50000
  const int E = in_sizes[1];         // 1600000
  const size_t NC2 = (size_t)N * CDIM * 2;  // bf16 plane: 25.6 MB
  const size_t NC1 = (size_t)N * CDIM;      // fp8 plane: 12.8 MB

  // Workspace layout (lifetime overlays):
  //   [0,NC2) q | hid (bf16 50000x512 = 2*NC2) overlays q+k8/v8 after edge_agg
  //   [NC2,2NC2) k8 (fp8) + v8 (fp8), each NC1
  //   [2NC2,3NC2) h (bf16, written by k_projln)
  //   [3NC2,4NC2) wv | featb(bf16) overlays (disjoint lifetime)
  //   [4NC2,..) CSR, then bf16 weights (Wq,Wk,Wv contiguous = fused Wqkv)
  char* w = (char*)d_ws;
  ushort* q   = (ushort*)(w);
  unsigned char* k8 = (unsigned char*)(w + NC2);
  unsigned char* v8 = (unsigned char*)(w + NC2 + NC1);
  ushort* wvb = (ushort*)(w + 3 * NC2);
  ushort* featb = (ushort*)(w + 3 * NC2);
  ushort* h   = (ushort*)(w + 2 * NC2);
  ushort* hid = (ushort*)(w);              // overlays q/k8/v8 (dead after proj)

  char* csr = w + 4 * NC2;
  int* rowptr  = (int*)(csr);
  int* deg     = (int*)(csr + 200064);
  int* csr_src = (int*)(csr + 400128);
  int* bsum    = (int*)(csr + 400128 + (size_t)E * 4);

  char* wb = csr + 400128 + (size_t)E * 4 + 256;
  ushort* Wqb = (ushort*)(wb);
  ushort* Wkb = (ushort*)(wb + 131072);
  ushort* Wvb = (ushort*)(wb + 262144);
  ushort* Wpb = (ushort*)(wb + 393216);
  ushort* W1b = (ushort*)(wb + 524288);
  ushort* W2b = (ushort*)(wb + 1048576);

  const int nb = (N + 1023) / 1024;
  const int RT128 = (N + 127) / 128; // 391

  // weight casts (one launch; Wq/Wk/Wv land contiguously -> fused Wqkv)
  k_castw<<<dim3(256, 6), 256, 0, stream>>>((const float4*)Wq, (ushort4*)Wqb,
                                            (const float4*)Wk, (ushort4*)Wkb,
                                            (const float4*)Wv, (ushort4*)Wvb,
                                            (const float4*)Wp, (ushort4*)Wpb,
                                            (const float4*)W1, (ushort4*)W1b,
                                            (const float4*)W2, (ushort4*)W2b);
  {
    int n4 = N * CDIM / 4;
    k_cast4<<<(n4 + 255) / 256, 256, 0, stream>>>((const float4*)feat, (ushort4*)featb, n4);
  }

  // CSR build (group edges by dst)
  hipMemsetAsync(deg, 0, (size_t)N * 4, stream);
  k_hist<<<(E + 255) / 256, 256, 0, stream>>>(edst, E, deg);
  k_scan1<<<nb, 1024, 0, stream>>>(deg, N, rowptr, bsum);
  k_scan2<<<1, 64, 0, stream>>>(bsum, nb);
  k_scan3<<<(N + 255) / 256, 256, 0, stream>>>(rowptr, bsum, N);
  hipMemsetAsync(deg, 0, (size_t)N * 4, stream);
  k_scatter<<<(E + 255) / 256, 256, 0, stream>>>(esrc, edst, E, rowptr, deg, csr_src);

  // fused QKV projection (q bf16; k/v fp8 planes), 128x256 blocks
  k_qkvf<<<dim3(RT128, 3), 512, 0, stream>>>(featb, Wqb, bq, bk, bv, q, k8, v8, N);
  // fused segment-softmax + aggregate (wave-per-dst, prefetched fp8 gathers)
  k_edge_agg<<<(N + 3) / 4, 256, 0, stream>>>(q, k8, v8, rowptr, csr_src, N, wvb);
  // out = x = feat + wv@Wp^T + bp; h = LN(x) — fused, no x round-trip
  k_projln<<<RT128, 512, 0, stream>>>(wvb, Wpb, bp, feat, lng, lnb, (float*)d_out, h, N);

  // MLP: hidden in 2 passes of 512 cols; 128x256 staged GEMMs.
  for (int c = 0; c < 2; ++c) {
    k_g1<<<dim3(RT128, 2), 512, 0, stream>>>(h, W1b + (size_t)c * 512 * CDIM,
                                             b1 + c * 512, hid, N);
    k_g2<<<RT128, 512, 0, stream>>>(hid, W2b + (size_t)c * 512,
                                    b2, (float*)d_out, N, c == 0 ? 1 : 0);
  }
}

// Round 12
// 681.046 us; speedup vs baseline: 1.1034x; 1.0091x over previous
//
#include <hip/hip_runtime.h>
#include <hip/hip_bf16.h>

#define CDIM 256
#define NH 8
#define HDIM 32

typedef short bf8 __attribute__((ext_vector_type(8)));
typedef float f32x4 __attribute__((ext_vector_type(4)));
typedef float f32x2 __attribute__((ext_vector_type(2)));

__device__ __forceinline__ float bf2f(ushort u) {
  union { unsigned int i; float f; } x; x.i = ((unsigned int)u) << 16; return x.f;
}
__device__ __forceinline__ ushort f2bf(float f) {
  union { float f; unsigned int i; } x; x.f = f;
  unsigned int lsb = (x.i >> 16) & 1u;
  unsigned int r = x.i + 0x7fffu + lsb;
  return (ushort)(r >> 16);
}

// ---------------- fp8 e4m3fn helpers (HW converts; guarded SW fallback) ----------------
__device__ __forceinline__ float dec_e4m3_sw(unsigned int b) {
  unsigned int s = b >> 7, e = (b >> 3) & 15, m = b & 7;
  float v = (e == 0) ? (float)m * 0.001953125f
                     : (float)(8 + m) * 0.125f * exp2f((float)((int)e - 7));
  return s ? -v : v;
}
__device__ __forceinline__ unsigned char enc_e4m3_sw(float f) {
  union { float f; unsigned int u; } x; x.f = f;
  unsigned int s = (x.u >> 31) << 7;
  float a = fabsf(f);
  if (!(a > 0.f)) return (unsigned char)s;
  if (a > 448.f) a = 448.f;
  int e = 0; float mant = frexpf(a, &e);
  int E = e + 6;
  unsigned int out;
  if (E <= 0) {
    int m = (int)rintf(a * 512.f);
    out = (m > 7) ? (s | (1u << 3)) : (s | (unsigned)m);
  } else {
    int m = (int)rintf(mant * 16.f);
    if (m == 16) { m = 8; E++; }
    if (E > 15 || (E == 15 && m - 8 > 6)) { E = 15; m = 14; }
    out = s | ((unsigned)E << 3) | (unsigned)(m - 8);
  }
  return (unsigned char)out;
}
template <bool HI>
__device__ __forceinline__ f32x2 fp8x2_f32(unsigned int w) {
#if __has_builtin(__builtin_amdgcn_cvt_pk_f32_fp8)
  return __builtin_amdgcn_cvt_pk_f32_fp8(w, HI);
#else
  unsigned int b0 = HI ? ((w >> 16) & 0xffu) : (w & 0xffu);
  unsigned int b1 = HI ? (w >> 24) : ((w >> 8) & 0xffu);
  f32x2 r; r[0] = dec_e4m3_sw(b0); r[1] = dec_e4m3_sw(b1); return r;
#endif
}
__device__ __forceinline__ unsigned char f32_fp8(float f) {
#if __has_builtin(__builtin_amdgcn_cvt_pk_fp8_f32)
  return (unsigned char)(__builtin_amdgcn_cvt_pk_fp8_f32(f, f, 0, false) & 0xff);
#else
  return enc_e4m3_sw(f);
#endif
}

// fast gelu (tanh form): max err ~2e-4 where pre-acts live (sigma~0.32).
__device__ __forceinline__ float fast_gelu(float t) {
  float u = 0.7978845608028654f * (t + 0.044715f * t * t * t);
  float ez = __expf(2.f * u);
  float th = 1.f - 2.f * __builtin_amdgcn_rcpf(ez + 1.f);
  return 0.5f * t * (1.f + th);
}

// async global->LDS, 16B per lane; LDS dest = wave-uniform base + lane*16.
__device__ __forceinline__ void gload_lds16(const ushort* g, ushort* l) {
  __builtin_amdgcn_global_load_lds((const __attribute__((address_space(1))) unsigned int*)g,
                                   (__attribute__((address_space(3))) unsigned int*)l,
                                   16, 0, 0);
}

// ---------------- casts fp32 -> bf16 (vectorized) ----------------
__global__ void k_cast4(const float4* __restrict__ s, ushort4* __restrict__ d, int n4) {
  int i = blockIdx.x * blockDim.x + threadIdx.x;
  if (i < n4) {
    float4 v = s[i];
    ushort4 o;
    o.x = f2bf(v.x); o.y = f2bf(v.y); o.z = f2bf(v.z); o.w = f2bf(v.w);
    d[i] = o;
  }
}

// merged weight casts: blockIdx.y selects region (saves 5 launches).
__global__ void k_castw(const float4* __restrict__ s0, ushort4* __restrict__ d0,
                        const float4* __restrict__ s1, ushort4* __restrict__ d1,
                        const float4* __restrict__ s2, ushort4* __restrict__ d2,
                        const float4* __restrict__ s3, ushort4* __restrict__ d3,
                        const float4* __restrict__ s4, ushort4* __restrict__ d4,
                        const float4* __restrict__ s5, ushort4* __restrict__ d5) {
  int y = blockIdx.y;
  const float4* s; ushort4* d; int n4;
  switch (y) {
    case 0: s = s0; d = d0; n4 = 16384; break;
    case 1: s = s1; d = d1; n4 = 16384; break;
    case 2: s = s2; d = d2; n4 = 16384; break;
    case 3: s = s3; d = d3; n4 = 16384; break;
    case 4: s = s4; d = d4; n4 = 65536; break;
    default: s = s5; d = d5; n4 = 65536; break;
  }
  int i = blockIdx.x * blockDim.x + threadIdx.x;
  if (i < n4) {
    float4 v = s[i];
    ushort4 o;
    o.x = f2bf(v.x); o.y = f2bf(v.y); o.z = f2bf(v.z); o.w = f2bf(v.w);
    d[i] = o;
  }
}

// ---------------- CSR build ----------------
__global__ void k_hist(const int* __restrict__ dst, int E, int* __restrict__ deg) {
  int i = blockIdx.x * blockDim.x + threadIdx.x;
  if (i < E) atomicAdd(&deg[dst[i]], 1);
}

__global__ __launch_bounds__(1024) void k_scan1(const int* __restrict__ deg, int N,
                                                int* __restrict__ rowptr, int* __restrict__ bsum) {
  __shared__ int s[1024];
  int t = threadIdx.x;
  int i = blockIdx.x * 1024 + t;
  int val = (i < N) ? deg[i] : 0;
  s[t] = val;
  __syncthreads();
  for (int off = 1; off < 1024; off <<= 1) {
    int add = (t >= off) ? s[t - off] : 0;
    __syncthreads();
    s[t] += add;
    __syncthreads();
  }
  if (i < N) rowptr[i + 1] = s[t];
  if (t == 1023) bsum[blockIdx.x] = s[t];
}

__global__ void k_scan2(int* __restrict__ bsum, int nb) {
  if (threadIdx.x == 0 && blockIdx.x == 0) {
    int run = 0;
    for (int j = 0; j < nb; ++j) { int t = bsum[j]; bsum[j] = run; run += t; }
  }
}

__global__ void k_scan3(int* __restrict__ rowptr, const int* __restrict__ bsum, int N) {
  int i = blockIdx.x * blockDim.x + threadIdx.x;
  if (i < N) rowptr[i + 1] += bsum[i >> 10];
  if (i == 0) rowptr[0] = 0;
}

__global__ void k_scatter(const int* __restrict__ src, const int* __restrict__ dst, int E,
                          const int* __restrict__ rowptr, int* __restrict__ cur,
                          int* __restrict__ csr_src) {
  int i = blockIdx.x * blockDim.x + threadIdx.x;
  if (i < E) {
    int d = dst[i];
    int pos = rowptr[d] + atomicAdd(&cur[d], 1);
    csr_src[pos] = src[i];
  }
}

// ---------------- pipelined 128x256 GEMM core (512 threads / 8 waves) ----------------
// Double-buffered LDS + COUNTED vmcnt (T4, m218): stage(t+1) is issued before
// compute(t) and stays in flight ACROSS the barrier — s_waitcnt vmcnt(3) waits
// only for tile t's 3 loads (each wave issues exactly 3 gload_lds per stage:
// 1 for A, 2 for B; vmcnt retires in order, m135). Raw s_barrier (no vmcnt(0)
// drain — r10 showed __syncthreads' drain defeats double-buffering).
// Barrier #2 (end of iter) orders this tile's LDS reads before its buffer is
// re-staged next iteration. sched_barrier(0) after barrier #1 guards against
// ds_read hoisting above the waitcnt (rule #18).
// Swizzle: LDS granule (row, slot) holds src granule (row, slot^(row&3)) —
// involution on SOURCE address here and on the READ below (G21).
__device__ __forceinline__ void stageA8(const ushort* __restrict__ S, int ld,
                                        int r0, int nr, int k0,
                                        ushort* lds, int wave, int lane) {
  int g = wave * 64 + lane;           // granule 0..511 (128 rows x 4 slots)
  int row = g >> 2, slot = g & 3;
  int rr = r0 + row; rr = (rr < nr) ? rr : (nr - 1);
  const ushort* src = S + (size_t)rr * ld + k0 + ((slot ^ (row & 3)) << 3);
  gload_lds16(src, &lds[(size_t)(wave * 64) * 8]);
}

__device__ __forceinline__ void stageB8(const ushort* __restrict__ S, int ld,
                                        int r0, int nr, int k0,
                                        ushort* lds, int wave, int lane) {
#pragma unroll
  for (int j = 0; j < 2; ++j) {
    int g = wave * 128 + j * 64 + lane;  // granule 0..1023 (256 rows x 4 slots)
    int row = g >> 2, slot = g & 3;
    int rr = r0 + row; rr = (rr < nr) ? rr : (nr - 1);
    const ushort* src = S + (size_t)rr * ld + k0 + ((slot ^ (row & 3)) << 3);
    gload_lds16(src, &lds[(size_t)(wave * 128 + j * 64) * 8]);
  }
}

// Wave w: rows (w&1)*64, cols (w>>1)*64 of the 128x256 block tile.
// lA: 2 x 128x32 buffers; lB: 2 x 256x32 buffers (48 KB total).
__device__ __forceinline__ void gemm256_core(const ushort* __restrict__ A, int lda, int rowt, int nA,
                                             const ushort* __restrict__ B, int ldb, int colt, int nB,
                                             int K, ushort* lA, ushort* lB, f32x4* acc) {
  int tid = threadIdx.x;
  int wave = tid >> 6, lane = tid & 63;
  int m = lane & 15, quad = lane >> 4;
  int r0w = (wave & 1) * 64, c0w = (wave >> 1) * 64;
  int sw = (quad ^ (m & 3)) << 3;  // swizzled 16B slot (in ushorts)

  int nt = K >> 5;
  // prologue: stage tile 0 into buffer 0 (3 VMEM ops per wave)
  stageA8(A, lda, rowt, nA, 0, lA, wave, lane);
  stageB8(B, ldb, colt, nB, 0, lB, wave, lane);

#pragma unroll
  for (int t = 0; t < 16; ++t) {
    if (t >= nt) break;
    int cur = t & 1;
    // issue next tile into the other buffer; its 3 loads stay in flight
    // across the barrier (counted wait below leaves them pending).
    if (t + 1 < nt) {
      stageA8(A, lda, rowt, nA, (t + 1) << 5, lA + (cur ^ 1) * (128 * 32), wave, lane);
      stageB8(B, ldb, colt, nB, (t + 1) << 5, lB + (cur ^ 1) * (256 * 32), wave, lane);
      asm volatile("s_waitcnt vmcnt(3)" ::: "memory");  // tile t's 3 loads done
    } else {
      asm volatile("s_waitcnt vmcnt(0)" ::: "memory");  // last tile: drain
    }
    __builtin_amdgcn_s_barrier();       // all waves' tile-t data in LDS
    __builtin_amdgcn_sched_barrier(0);  // don't hoist ds_reads above the wait

    const ushort* cA = lA + cur * (128 * 32);
    const ushort* cB = lB + cur * (256 * 32);
    bf8 a[4], b[4];
#pragma unroll
    for (int ri = 0; ri < 4; ++ri)
      a[ri] = *(const bf8*)&cA[(r0w + ri * 16 + m) * 32 + sw];
#pragma unroll
    for (int cj = 0; cj < 4; ++cj)
      b[cj] = *(const bf8*)&cB[(c0w + cj * 16 + m) * 32 + sw];
#pragma unroll
    for (int ri = 0; ri < 4; ++ri)
#pragma unroll
      for (int cj = 0; cj < 4; ++cj)
        acc[ri * 4 + cj] = __builtin_amdgcn_mfma_f32_16x16x32_bf16(a[ri], b[cj], acc[ri * 4 + cj], 0, 0, 0);

    __builtin_amdgcn_s_barrier();  // tile-t reads done before buffer reuse
  }
}

// fused QKV: q (bf16) | k,v (fp8). Grid (391, 3); blockIdx.y picks q/k/v.
__global__ __launch_bounds__(512) void k_qkvf(const ushort* __restrict__ featb,
                                              const ushort* __restrict__ Wqkv,
                                              const float* __restrict__ bq, const float* __restrict__ bk,
                                              const float* __restrict__ bv,
                                              ushort* __restrict__ q,
                                              unsigned char* __restrict__ k8,
                                              unsigned char* __restrict__ v8, int N) {
  __shared__ ushort lA[2 * 128 * 32];
  __shared__ ushort lB[2 * 256 * 32];
  int rowt = blockIdx.x * 128;
  int which = blockIdx.y;
  const float* bias = (which == 0) ? bq : (which == 1) ? bk : bv;
  int tid = threadIdx.x;
  int wave = tid >> 6, lane = tid & 63, m = lane & 15, quad = lane >> 4;
  int r0w = (wave & 1) * 64, c0w = (wave >> 1) * 64;

  f32x4 acc[16];
#pragma unroll
  for (int j = 0; j < 16; ++j) acc[j] = (f32x4){0.f, 0.f, 0.f, 0.f};

  gemm256_core(featb, CDIM, rowt, N, Wqkv + (size_t)which * 256 * CDIM, CDIM, 0, 256,
               CDIM, lA, lB, acc);

  unsigned char* o8 = (which == 1) ? k8 : v8;
#pragma unroll
  for (int cj = 0; cj < 4; ++cj) {
    int col = c0w + cj * 16 + m;
    float bs = bias[col];
#pragma unroll
    for (int ri = 0; ri < 4; ++ri)
#pragma unroll
      for (int i = 0; i < 4; ++i) {
        int r = rowt + r0w + ri * 16 + quad * 4 + i;
        if (r < N) {
          float vv = acc[ri * 4 + cj][i] + bs;
          if (which == 0) q[(size_t)r * CDIM + col] = f2bf(vv);
          else            o8[(size_t)r * CDIM + col] = f32_fp8(vv);
        }
      }
  }
}

// x = feat + wv@Wp^T + bp, FUSED with LayerNorm: out = x; h = LN(x)*g + b.
__global__ __launch_bounds__(512) void k_projln(const ushort* __restrict__ wv,
                                                const ushort* __restrict__ Wp,
                                                const float* __restrict__ bp,
                                                const float* __restrict__ feat,
                                                const float* __restrict__ lng,
                                                const float* __restrict__ lnb,
                                                float* __restrict__ out,
                                                ushort* __restrict__ h, int N) {
  __shared__ ushort lA[2 * 128 * 32];
  __shared__ ushort lB[2 * 256 * 32];
  __shared__ float sred[2][128][4];  // [s|ss][block-row][col-quadrant]
  int rowt = blockIdx.x * 128;
  int tid = threadIdx.x;
  int wave = tid >> 6, lane = tid & 63, m = lane & 15, quad = lane >> 4;
  int r0w = (wave & 1) * 64, c0w = (wave >> 1) * 64;

  f32x4 acc[16];
#pragma unroll
  for (int j = 0; j < 16; ++j) acc[j] = (f32x4){0.f, 0.f, 0.f, 0.f};

  gemm256_core(wv, CDIM, rowt, N, Wp, CDIM, 0, 256, CDIM, lA, lB, acc);

  // acc <- x = acc + bp + feat (row-clamped feat read for tail rows)
#pragma unroll
  for (int cj = 0; cj < 4; ++cj) {
    int col = c0w + cj * 16 + m;
    float bs = bp[col];
#pragma unroll
    for (int ri = 0; ri < 4; ++ri)
#pragma unroll
      for (int i = 0; i < 4; ++i) {
        int r = rowt + r0w + ri * 16 + quad * 4 + i;
        int rr = (r < N) ? r : (N - 1);
        acc[ri * 4 + cj][i] += bs + feat[(size_t)rr * CDIM + col];
      }
  }

  // per-row partial sums over this wave's 64-col quadrant
#pragma unroll
  for (int ri = 0; ri < 4; ++ri)
#pragma unroll
    for (int i = 0; i < 4; ++i) {
      float s = acc[ri * 4 + 0][i] + acc[ri * 4 + 1][i] + acc[ri * 4 + 2][i] + acc[ri * 4 + 3][i];
      float ss = acc[ri * 4 + 0][i] * acc[ri * 4 + 0][i] + acc[ri * 4 + 1][i] * acc[ri * 4 + 1][i]
               + acc[ri * 4 + 2][i] * acc[ri * 4 + 2][i] + acc[ri * 4 + 3][i] * acc[ri * 4 + 3][i];
#pragma unroll
      for (int msk = 1; msk <= 8; msk <<= 1) {
        s += __shfl_xor(s, msk);
        ss += __shfl_xor(ss, msk);
      }
      if (m == 0) {
        int blrow = (wave & 1) * 64 + ri * 16 + quad * 4 + i;
        sred[0][blrow][wave >> 1] = s;
        sred[1][blrow][wave >> 1] = ss;
      }
    }
  __syncthreads();

  float mu_[16], rs_[16];
#pragma unroll
  for (int ri = 0; ri < 4; ++ri)
#pragma unroll
    for (int i = 0; i < 4; ++i) {
      int blrow = (wave & 1) * 64 + ri * 16 + quad * 4 + i;
      float S = sred[0][blrow][0] + sred[0][blrow][1] + sred[0][blrow][2] + sred[0][blrow][3];
      float SS = sred[1][blrow][0] + sred[1][blrow][1] + sred[1][blrow][2] + sred[1][blrow][3];
      float mu = S * (1.f / CDIM);
      float var = SS * (1.f / CDIM) - mu * mu;
      mu_[ri * 4 + i] = mu;
      rs_[ri * 4 + i] = rsqrtf(var + 1e-5f);
    }

#pragma unroll
  for (int cj = 0; cj < 4; ++cj) {
    int col = c0w + cj * 16 + m;
    float gc = lng[col], bc = lnb[col];
#pragma unroll
    for (int ri = 0; ri < 4; ++ri)
#pragma unroll
      for (int i = 0; i < 4; ++i) {
        int r = rowt + r0w + ri * 16 + quad * 4 + i;
        if (r < N) {
          float v = acc[ri * 4 + cj][i];
          out[(size_t)r * CDIM + col] = v;
          h[(size_t)r * CDIM + col] = f2bf((v - mu_[ri * 4 + i]) * rs_[ri * 4 + i] * gc + bc);
        }
      }
  }
}

// hidden-chunk GEMM: hid[., colt..colt+256) = gelu(h @ W1c^T + b1c). Grid (391, 2).
__global__ __launch_bounds__(512) void k_g1(const ushort* __restrict__ h,
                                            const ushort* __restrict__ W1c,
                                            const float* __restrict__ b1c,
                                            ushort* __restrict__ hid, int N) {
  __shared__ ushort lA[2 * 128 * 32];
  __shared__ ushort lB[2 * 256 * 32];
  int rowt = blockIdx.x * 128, colt = blockIdx.y * 256;
  int tid = threadIdx.x;
  int wave = tid >> 6, lane = tid & 63, m = lane & 15, quad = lane >> 4;
  int r0w = (wave & 1) * 64, c0w = (wave >> 1) * 64;

  f32x4 acc[16];
#pragma unroll
  for (int j = 0; j < 16; ++j) acc[j] = (f32x4){0.f, 0.f, 0.f, 0.f};

  gemm256_core(h, CDIM, rowt, N, W1c, CDIM, colt, 512, CDIM, lA, lB, acc);

#pragma unroll
  for (int cj = 0; cj < 4; ++cj) {
    int col = colt + c0w + cj * 16 + m;  // hidden-local col, < 512
    float bs = b1c[col];
#pragma unroll
    for (int ri = 0; ri < 4; ++ri)
#pragma unroll
      for (int i = 0; i < 4; ++i) {
        int r = rowt + r0w + ri * 16 + quad * 4 + i;
        if (r < N) hid[(size_t)r * 512 + col] = f2bf(fast_gelu(acc[ri * 4 + cj][i] + bs));
      }
  }
}

// out-chunk GEMM: out += hid @ W2c^T (+ b2 on first pass). Grid (391).
__global__ __launch_bounds__(512) void k_g2(const ushort* __restrict__ hid,
                                            const ushort* __restrict__ W2c,
                                            const float* __restrict__ b2,
                                            float* __restrict__ out, int N, int first) {
  __shared__ ushort lA[2 * 128 * 32];
  __shared__ ushort lB[2 * 256 * 32];
  int rowt = blockIdx.x * 128;
  int tid = threadIdx.x;
  int wave = tid >> 6, lane = tid & 63, m = lane & 15, quad = lane >> 4;
  int r0w = (wave & 1) * 64, c0w = (wave >> 1) * 64;

  f32x4 acc[16];
#pragma unroll
  for (int j = 0; j < 16; ++j) acc[j] = (f32x4){0.f, 0.f, 0.f, 0.f};

  gemm256_core(hid, 512, rowt, N, W2c, 1024, 0, 256, 512, lA, lB, acc);

#pragma unroll
  for (int cj = 0; cj < 4; ++cj) {
    int col = c0w + cj * 16 + m;
    float bs = first ? b2[col] : 0.f;
#pragma unroll
    for (int ri = 0; ri < 4; ++ri)
#pragma unroll
      for (int i = 0; i < 4; ++i) {
        int r = rowt + r0w + ri * 16 + quad * 4 + i;
        if (r < N) {
          size_t idx = (size_t)r * CDIM + col;
          out[idx] = out[idx] + acc[ri * 4 + cj][i] + bs;
        }
      }
  }
}

// fused segment softmax + aggregate, wave-per-dst, barrier-free, fp8 K/V,
// one-chunk software prefetch of csr_src + K rows (round-9 proven version).
__global__ __launch_bounds__(256) void k_edge_agg(const ushort* __restrict__ q,
                                                  const unsigned char* __restrict__ kk8,
                                                  const unsigned char* __restrict__ vv8,
                                                  const int* __restrict__ rowptr,
                                                  const int* __restrict__ csr_src,
                                                  int N,
                                                  ushort* __restrict__ wv) {
  int wave = threadIdx.x >> 6, lane = threadIdx.x & 63;
  int n = blockIdx.x * 4 + wave;
  if (n >= N) return;  // wave-uniform; no barriers in this kernel

  int el = lane >> 3, h = lane & 7;
  int beg = rowptr[n], end = rowptr[n + 1];
  int deg = end - beg;

  // q slice for head h into registers (f32)
  float qf[32];
  {
    const ushort* qp = q + (size_t)n * CDIM + h * HDIM;
#pragma unroll
    for (int g = 0; g < 4; ++g) {
      bf8 qv = *(const bf8*)(qp + g * 8);
#pragma unroll
      for (int j = 0; j < 8; ++j) qf[g * 8 + j] = bf2f((ushort)qv[j]);
    }
  }

  float accv[4] = {0.f, 0.f, 0.f, 0.f};
  float den_part = 0.f;

  // prefetch chunk 0 (invalid lanes read row 0 — harmless, e forced to 0)
  int src_n = (el < deg) ? csr_src[beg + el] : 0;
  const unsigned char* kp0 = kk8 + (size_t)src_n * CDIM + h * HDIM;
  uint4 w0_n = *(const uint4*)kp0;
  uint4 w1_n = *(const uint4*)(kp0 + 16);

  for (int c0 = 0; c0 < deg; c0 += 8) {
    int src = src_n;
    uint4 w0 = w0_n, w1 = w1_n;
    bool vcur = (c0 + el < deg);

    // issue next chunk's loads before consuming this chunk (latency overlap)
    src_n = (c0 + 8 + el < deg) ? csr_src[beg + c0 + 8 + el] : 0;
    const unsigned char* kpn = kk8 + (size_t)src_n * CDIM + h * HDIM;
    w0_n = *(const uint4*)kpn;
    w1_n = *(const uint4*)(kpn + 16);

    float e = 0.f;
    if (vcur) {
      unsigned int ws[8] = {w0.x, w0.y, w0.z, w0.w, w1.x, w1.y, w1.z, w1.w};
      float dot = 0.f;
#pragma unroll
      for (int j = 0; j < 8; ++j) {
        f32x2 lo = fp8x2_f32<false>(ws[j]);
        f32x2 hi = fp8x2_f32<true>(ws[j]);
        dot = fmaf(qf[j * 4 + 0], lo[0], dot);
        dot = fmaf(qf[j * 4 + 1], lo[1], dot);
        dot = fmaf(qf[j * 4 + 2], hi[0], dot);
        dot = fmaf(qf[j * 4 + 3], hi[1], dot);
      }
      float s = dot * 0.17677669529663687f;  // 1/sqrt(32)
      s = fminf(10.f, fmaxf(-10.f, s));
      e = __expf(s - 10.f);  // fixed shift: scores clamped, softmax shift-invariant
    }
    den_part += e;

    // aggregate these 8 edges: lane reads its 4 channels of V[src_j], weight e_j[head]
#pragma unroll
    for (int j = 0; j < 8; ++j) {
      int sj = __shfl(src, j << 3);
      float ej = __shfl(e, (j << 3) | (lane >> 3));
      unsigned int vw = *(const unsigned int*)(vv8 + (size_t)sj * CDIM + lane * 4);
      f32x2 lo = fp8x2_f32<false>(vw);
      f32x2 hi = fp8x2_f32<true>(vw);
      accv[0] = fmaf(ej, lo[0], accv[0]);
      accv[1] = fmaf(ej, lo[1], accv[1]);
      accv[2] = fmaf(ej, hi[0], accv[2]);
      accv[3] = fmaf(ej, hi[1], accv[3]);
    }
  }

  // den[h] = sum over el lanes (xor over bits 3..5), broadcast to channel lanes
  float den = den_part;
  den += __shfl_xor(den, 8);
  den += __shfl_xor(den, 16);
  den += __shfl_xor(den, 32);
  float denh = __shfl(den, lane >> 3);

  float inv = (deg > 0) ? (1.f / denh) : 0.f;
  ushort4 o;
  o.x = f2bf(accv[0] * inv);
  o.y = f2bf(accv[1] * inv);
  o.z = f2bf(accv[2] * inv);
  o.w = f2bf(accv[3] * inv);
  *(ushort4*)(wv + (size_t)n * CDIM + lane * 4) = o;
}

extern "C" void kernel_launch(void* const* d_in, const int* in_sizes, int n_in,
                              void* d_out, int out_size, void* d_ws, size_t ws_size,
                              hipStream_t stream) {
  const float* feat = (const float*)d_in[0];
  const int* esrc = (const int*)d_in[1];
  const int* edst = (const int*)d_in[2];
  const float* Wq = (const float*)d_in[3];
  const float* bq = (const float*)d_in[4];
  const float* Wk = (const float*)d_in[5];
  const float* bk = (const float*)d_in[6];
  const float* Wv = (const float*)d_in[7];
  const float* bv = (const float*)d_in[8];
  const float* Wp = (const float*)d_in[9];
  const float* bp = (const float*)d_in[10];
  const float* lng = (const float*)d_in[11];
  const float* lnb = (const float*)d_in[12];
  const float* W1 = (const float*)d_in[13];
  const float* b1 = (const float*)d_in[14];
  const float* W2 = (const float*)d_in[15];
  const float* b2 = (const float*)d_in[16];

  const int N = in_sizes[0] / CDIM;  // 50000
  const int E = in_sizes[1];         // 1600000
  const size_t NC2 = (size_t)N * CDIM * 2;  // bf16 plane: 25.6 MB
  const size_t NC1 = (size_t)N * CDIM;      // fp8 plane: 12.8 MB

  // Workspace layout (lifetime overlays):
  //   [0,NC2) q | hid (bf16 50000x512 = 2*NC2) overlays q+k8/v8 after edge_agg
  //   [NC2,2NC2) k8 (fp8) + v8 (fp8), each NC1
  //   [2NC2,3NC2) h (bf16, written by k_projln)
  //   [3NC2,4NC2) wv | featb(bf16) overlays (disjoint lifetime)
  //   [4NC2,..) CSR, then bf16 weights (Wq,Wk,Wv contiguous = fused Wqkv)
  char* w = (char*)d_ws;
  ushort* q   = (ushort*)(w);
  unsigned char* k8 = (unsigned char*)(w + NC2);
  unsigned char* v8 = (unsigned char*)(w + NC2 + NC1);
  ushort* wvb = (ushort*)(w + 3 * NC2);
  ushort* featb = (ushort*)(w + 3 * NC2);
  ushort* h   = (ushort*)(w + 2 * NC2);
  ushort* hid = (ushort*)(w);              // overlays q/k8/v8 (dead after proj)

  char* csr = w + 4 * NC2;
  int* rowptr  = (int*)(csr);
  int* deg     = (int*)(csr + 200064);
  int* csr_src = (int*)(csr + 400128);
  int* bsum    = (int*)(csr + 400128 + (size_t)E * 4);

  char* wb = csr + 400128 + (size_t)E * 4 + 256;
  ushort* Wqb = (ushort*)(wb);
  ushort* Wkb = (ushort*)(wb + 131072);
  ushort* Wvb = (ushort*)(wb + 262144);
  ushort* Wpb = (ushort*)(wb + 393216);
  ushort* W1b = (ushort*)(wb + 524288);
  ushort* W2b = (ushort*)(wb + 1048576);

  const int nb = (N + 1023) / 1024;
  const int RT128 = (N + 127) / 128; // 391

  // weight casts (one launch; Wq/Wk/Wv land contiguously -> fused Wqkv)
  k_castw<<<dim3(256, 6), 256, 0, stream>>>((const float4*)Wq, (ushort4*)Wqb,
                                            (const float4*)Wk, (ushort4*)Wkb,
                                            (const float4*)Wv, (ushort4*)Wvb,
                                            (const float4*)Wp, (ushort4*)Wpb,
                                            (const float4*)W1, (ushort4*)W1b,
                                            (const float4*)W2, (ushort4*)W2b);
  {
    int n4 = N * CDIM / 4;
    k_cast4<<<(n4 + 255) / 256, 256, 0, stream>>>((const float4*)feat, (ushort4*)featb, n4);
  }

  // CSR build (group edges by dst)
  hipMemsetAsync(deg, 0, (size_t)N * 4, stream);
  k_hist<<<(E + 255) / 256, 256, 0, stream>>>(edst, E, deg);
  k_scan1<<<nb, 1024, 0, stream>>>(deg, N, rowptr, bsum);
  k_scan2<<<1, 64, 0, stream>>>(bsum, nb);
  k_scan3<<<(N + 255) / 256, 256, 0, stream>>>(rowptr, bsum, N);
  hipMemsetAsync(deg, 0, (size_t)N * 4, stream);
  k_scatter<<<(E + 255) / 256, 256, 0, stream>>>(esrc, edst, E, rowptr, deg, csr_src);

  // fused QKV projection (q bf16; k/v fp8 planes), pipelined 128x256 blocks
  k_qkvf<<<dim3(RT128, 3), 512, 0, stream>>>(featb, Wqb, bq, bk, bv, q, k8, v8, N);
  // fused segment-softmax + aggregate (wave-per-dst, prefetched fp8 gathers)
  k_edge_agg<<<(N + 3) / 4, 256, 0, stream>>>(q, k8, v8, rowptr, csr_src, N, wvb);
  // out = x = feat + wv@Wp^T + bp; h = LN(x) — fused, no x round-trip
  k_projln<<<RT128, 512, 0, stream>>>(wvb, Wpb, bp, feat, lng, lnb, (float*)d_out, h, N);

  // MLP: hidden in 2 passes of 512 cols; pipelined 128x256 GEMMs.
  for (int c = 0; c < 2; ++c) {
    k_g1<<<dim3(RT128, 2), 512, 0, stream>>>(h, W1b + (size_t)c * 512 * CDIM,
                                             b1 + c * 512, hid, N);
    k_g2<<<RT128, 512, 0, stream>>>(hid, W2b + (size_t)c * 512,
                                    b2, (float*)d_out, N, c == 0 ? 1 : 0);
  }
}